// Round 1
// baseline (50.414 us; speedup 1.0000x reference)
//
#include <hip/hip_runtime.h>
#include <hip/hip_fp16.h>

// Problem constants (from reference)
#define N_REL 201   // NUM_RELS + 1 (includes PAD row 200, which is all-zero)
#define SEM 32      // SEM_DIM
#define KNEI 20     // K neighbors

// Workspace layout:
//   [0, 80804)        __half S[201*201] (+1 pad half at index 40401); region reserved to 80896
//   [80896, +51456)   float P[2][201][32]
#define S_HALFS 40402
#define S_BYTES 80896
#define P_FLOATS (2 * N_REL * SEM)  // 12864

// ---------------------------------------------------------------------------
// Kernel 1: build S = rel_emb @ rel_emb^T  (fp16) and P[h] = rel_emb @ W_h^T (fp32)
// grid = 201 blocks (one per relation row), 256 threads.
// LDS staging with +1-padded strides so dot-product reads are bank-conflict-free.
// ---------------------------------------------------------------------------
__global__ __launch_bounds__(256) void build_tables_kernel(
    const float* __restrict__ rel_emb,   // [201][64]
    const float* __restrict__ w,         // [32][128]  (row j: [W_out_j | W_in_j])
    __half* __restrict__ S,              // [201][201]
    float* __restrict__ P)               // [2][201][32]
{
  __shared__ float embL[N_REL * 65];   // stride 65: bank = (row + d) % 32
  __shared__ float wL[SEM * 129];      // stride 129: bank = (row + d) % 32
  const int t = threadIdx.x;
  for (int e = t; e < N_REL * 64; e += 256) {
    int r = e >> 6, d = e & 63;
    embL[r * 65 + d] = rel_emb[e];
  }
  for (int e = t; e < SEM * 128; e += 256) {
    int r = e >> 7, c = e & 127;
    wL[r * 129 + c] = w[e];
  }
  __syncthreads();

  const int i = blockIdx.x;  // 0..200
  // S row i: thread jj computes rel_emb[i] . rel_emb[jj]
  for (int jj = t; jj < N_REL; jj += 256) {
    float acc = 0.f;
#pragma unroll
    for (int d = 0; d < 64; ++d)
      acc = fmaf(embL[i * 65 + d], embL[jj * 65 + d], acc);
    S[i * N_REL + jj] = __float2half(acc);
  }
  // P rows for relation i: lanes 0..63 -> (half h, out-dim jj)
  if (t < 64) {
    int hh = t >> 5, jj = t & 31;
    float acc = 0.f;
#pragma unroll
    for (int d = 0; d < 64; ++d)
      acc = fmaf(embL[i * 65 + d], wL[jj * 129 + hh * 64 + d], acc);
    P[(hh * N_REL + i) * SEM + jj] = acc;
  }
  if (i == 0 && t == 0) S[N_REL * N_REL] = __float2half(0.f);  // pad for dword copy
}

// ---------------------------------------------------------------------------
// Kernel 2: one wave per node. lane = (h = lane>>5 : 0=out,1=in ; j = lane&31).
//   lanes j<20 of each half: score = S[idx][tgt] (one fp16 LDS read)
//   butterfly softmax within each 32-lane half (xor masks 16..1)
//   agg: acc_h[j] = sum_k att_k * P[h][idx_k][j]   (bank = j -> conflict-free)
//   ent[j] = sigmoid(acc_0[j] + acc_1[j] + b[j])   via shfl_xor(32)
//   out row n: [feat[n][0..31] | ent[0..31]]  -> 256 B contiguous store per wave
// 132 KB LDS -> 1 block/CU; 1024 threads -> 16 waves/CU.
// ---------------------------------------------------------------------------
__global__ __launch_bounds__(1024) void fuse_kernel(
    const int* __restrict__ out_nei, const int* __restrict__ in_nei,
    const int* __restrict__ target, const float* __restrict__ feat,
    const float* __restrict__ bias,
    const __half* __restrict__ S, const float* __restrict__ P,
    float* __restrict__ out, int n_nodes)
{
  __shared__ __align__(16) __half S_l[S_HALFS];
  __shared__ __align__(16) float P_l[P_FLOATS];
  const int t = threadIdx.x;
  {
    const unsigned int* s32 = (const unsigned int*)S;
    unsigned int* sl = (unsigned int*)S_l;
    for (int e = t; e < S_HALFS / 2; e += 1024) sl[e] = s32[e];
    const float4* p4 = (const float4*)P;
    float4* pl = (float4*)P_l;
    for (int e = t; e < P_FLOATS / 4; e += 1024) pl[e] = p4[e];
  }
  __syncthreads();

  const int lane = t & 63;
  const int h = lane >> 5;
  const int j = lane & 31;
  const int wave = blockIdx.x * (blockDim.x >> 6) + (t >> 6);
  const int nwaves = gridDim.x * (blockDim.x >> 6);
  const float bj = bias[j];
  const int* __restrict__ nei = h ? in_nei : out_nei;

  for (int n = wave; n < n_nodes; n += nwaves) {
    const int tgt = target[n];   // same addr across wave -> broadcast
    int idx = N_REL - 1;         // PAD (unused by inactive lanes)
    float sc = -1e30f;
    if (j < KNEI) {
      idx = nei[n * KNEI + j];
      sc = __half2float(S_l[idx * N_REL + tgt]);
    }
    // softmax over the 20 valid lanes of each 32-lane half
    float mx = sc;
#pragma unroll
    for (int m = 16; m >= 1; m >>= 1) mx = fmaxf(mx, __shfl_xor(mx, m, 64));
    float e = (j < KNEI) ? __expf(sc - mx) : 0.f;
    float s = e;
#pragma unroll
    for (int m = 16; m >= 1; m >>= 1) s += __shfl_xor(s, m, 64);
    const float a = __fdividef(e, s);

    // aggregation in pre-activation space
    float acc = 0.f;
    const int base = h << 5;
#pragma unroll
    for (int k = 0; k < KNEI; ++k) {
      float ak = __shfl(a, base + k, 64);
      int ik = __shfl(idx, base + k, 64);
      acc = fmaf(ak, P_l[(h * N_REL + ik) * SEM + j], acc);
    }
    // combine halves: lane (0,j) + lane (1,j)
    float tot = acc + __shfl_xor(acc, 32, 64);
    float ent = __fdividef(1.f, 1.f + __expf(-(tot + bj)));
    float val = h ? ent : feat[n * SEM + j];
    out[(size_t)n * 64 + lane] = val;
  }
}

extern "C" void kernel_launch(void* const* d_in, const int* in_sizes, int n_in,
                              void* d_out, int out_size, void* d_ws, size_t ws_size,
                              hipStream_t stream) {
  const int* out_nei   = (const int*)d_in[0];
  const int* in_nei    = (const int*)d_in[1];
  const int* target    = (const int*)d_in[2];
  const float* feat    = (const float*)d_in[3];
  const float* rel_emb = (const float*)d_in[4];
  const float* w       = (const float*)d_in[5];
  const float* bias    = (const float*)d_in[6];
  float* out = (float*)d_out;
  const int n_nodes = in_sizes[2];  // N = len(target_rels)

  __half* S = (__half*)d_ws;
  float* P  = (float*)((char*)d_ws + S_BYTES);

  build_tables_kernel<<<N_REL, 256, 0, stream>>>(rel_emb, w, S, P);
  fuse_kernel<<<256, 1024, 0, stream>>>(out_nei, in_nei, target, feat, bias, S, P,
                                        out, n_nodes);
}

// Round 2
// 48.335 us; speedup vs baseline: 1.0430x; 1.0430x over previous
//
#include <hip/hip_runtime.h>
#include <hip/hip_fp16.h>

// Problem constants (from reference)
#define N_REL 201   // NUM_RELS + 1 (includes PAD row 200, all-zero)
#define SEM 32      // SEM_DIM
#define KNEI 20     // K neighbors

// Workspace layout:
//   [0, 80804)        __half S[201*201] (+pad); region reserved to 80896
//   [80896, +51456)   float P[2][201][32]
#define S_BYTES 80896
#define P_FLOATS (2 * N_REL * SEM)  // 12864

// ---------------------------------------------------------------------------
// Kernel 1: build S = rel_emb @ rel_emb^T (fp16) and P[h] = rel_emb @ W_h^T (fp32)
// ---------------------------------------------------------------------------
__global__ __launch_bounds__(256) void build_tables_kernel(
    const float* __restrict__ rel_emb,   // [201][64]
    const float* __restrict__ w,         // [32][128]
    __half* __restrict__ S,              // [201][201]
    float* __restrict__ P)               // [2][201][32]
{
  __shared__ float embL[N_REL * 65];
  __shared__ float wL[SEM * 129];
  const int t = threadIdx.x;
  for (int e = t; e < N_REL * 64; e += 256) {
    int r = e >> 6, d = e & 63;
    embL[r * 65 + d] = rel_emb[e];
  }
  for (int e = t; e < SEM * 128; e += 256) {
    int r = e >> 7, c = e & 127;
    wL[r * 129 + c] = w[e];
  }
  __syncthreads();

  const int i = blockIdx.x;  // 0..200
  for (int jj = t; jj < N_REL; jj += 256) {
    float acc = 0.f;
#pragma unroll
    for (int d = 0; d < 64; ++d)
      acc = fmaf(embL[i * 65 + d], embL[jj * 65 + d], acc);
    S[i * N_REL + jj] = __float2half(acc);
  }
  if (t < 64) {
    int hh = t >> 5, jj = t & 31;
    float acc = 0.f;
#pragma unroll
    for (int d = 0; d < 64; ++d)
      acc = fmaf(embL[i * 65 + d], wL[jj * 129 + hh * 64 + d], acc);
    P[(hh * N_REL + i) * SEM + jj] = acc;
  }
}

// ---------------------------------------------------------------------------
// Kernel 2: one wave per node; lane = (h = lane>>5, j = lane&31).
//  - lanes j<20: gather packed {fp16 score | idx<<16} -> wave scratch (LDS)
//  - EVERY lane reads the 10 b64 pairs back (uniform addr -> broadcast),
//    computes max locally (packed hmax2 tree, zero shuffles), 20 local exps,
//    local sum, 20 FMAs vs LDS P rows (bank=j -> conflict-free).
//  - single cross-lane op: shfl_xor(.,32) to combine halves.
// LDS = P (51456 B) + scratch (4096 B) -> 2 blocks/CU -> 32 waves/CU.
// ---------------------------------------------------------------------------
__global__ __launch_bounds__(1024, 8) void fuse_kernel(
    const int* __restrict__ out_nei, const int* __restrict__ in_nei,
    const int* __restrict__ target, const float* __restrict__ feat,
    const float* __restrict__ bias,
    const __half* __restrict__ Sg,     // [201][201] global (L2-resident)
    const float* __restrict__ P,       // [2][201][32]
    float* __restrict__ out, int n_nodes)
{
  __shared__ __align__(16) float P_l[P_FLOATS];     // 51456 B
  __shared__ __align__(16) unsigned int scr[16 * 64]; // 4096 B, 256 B/wave
  const int t = threadIdx.x;
  {
    const float4* p4 = (const float4*)P;
    float4* pl = (float4*)P_l;
    for (int e = t; e < P_FLOATS / 4; e += 1024) pl[e] = p4[e];
  }
  __syncthreads();

  const int lane = t & 63;
  const int h = lane >> 5;
  const int j = lane & 31;
  const int wid = t >> 6;
  unsigned int* ws = &scr[(wid << 6) + (h << 5)];  // this half's 20 slots
  const float bj = bias[j];
  const int* __restrict__ nei = h ? in_nei : out_nei;
  const int hbase = h * (N_REL * SEM) + j;          // P_l row base for this half

  const int wave = blockIdx.x * (blockDim.x >> 6) + wid;
  const int nwaves = gridDim.x * (blockDim.x >> 6);

  for (int n = wave; n < n_nodes; n += nwaves) {
    const int tgt = target[n];                 // uniform -> broadcast load
    const float fv = feat[n * SEM + j];        // prefetch feat row
    if (j < KNEI) {
      const int idx = nei[n * KNEI + j];
      const __half sc = Sg[idx * N_REL + tgt];
      ws[j] = (unsigned int)__half_as_ushort(sc) | ((unsigned int)idx << 16);
    }
    // wave-synchronous: same-wave DS ops are ordered; compiler inserts lgkmcnt.

    // local max over the 20 packed scores (lo16 of each word)
    __half2 m2 = __halves2half2(__ushort_as_half((unsigned short)0xFC00),
                                __ushort_as_half((unsigned short)0xFC00)); // -inf
    uint2 q[10];
#pragma unroll
    for (int r = 0; r < 10; ++r) {
      q[r] = *(const uint2*)&ws[2 * r];        // broadcast read
      // lo16 fields hold scores; hi fields hold idx bits (garbage as f16) -> track lo only
      __half2 a = *(const __half2*)&q[r].x;
      __half2 b = *(const __half2*)&q[r].y;
      m2.x = __hmax(m2.x, a.x);
      m2.x = __hmax(m2.x, b.x);
    }
    const float mx = __half2float(m2.x);

    float s = 0.f, acc = 0.f;
#pragma unroll
    for (int r = 0; r < 10; ++r) {
#pragma unroll
      for (int u = 0; u < 2; ++u) {
        const unsigned int w32 = u ? q[r].y : q[r].x;
        const float sc = __half2float(__ushort_as_half((unsigned short)(w32 & 0xFFFFu)));
        const int idx = (int)(w32 >> 16);
        const float e = __expf(sc - mx);
        s += e;
        acc = fmaf(e, P_l[hbase + idx * SEM], acc);
      }
    }
    float rsum = __fdividef(acc, s);
    rsum += __shfl_xor(rsum, 32, 64);
    const float ent = __fdividef(1.f, 1.f + __expf(-(rsum + bj)));
    out[(size_t)n * 64 + lane] = h ? ent : fv;
  }
}

extern "C" void kernel_launch(void* const* d_in, const int* in_sizes, int n_in,
                              void* d_out, int out_size, void* d_ws, size_t ws_size,
                              hipStream_t stream) {
  const int* out_nei   = (const int*)d_in[0];
  const int* in_nei    = (const int*)d_in[1];
  const int* target    = (const int*)d_in[2];
  const float* feat    = (const float*)d_in[3];
  const float* rel_emb = (const float*)d_in[4];
  const float* w       = (const float*)d_in[5];
  const float* bias    = (const float*)d_in[6];
  float* out = (float*)d_out;
  const int n_nodes = in_sizes[2];

  __half* S = (__half*)d_ws;
  float* P  = (float*)((char*)d_ws + S_BYTES);

  build_tables_kernel<<<N_REL, 256, 0, stream>>>(rel_emb, w, S, P);
  fuse_kernel<<<512, 1024, 0, stream>>>(out_nei, in_nei, target, feat, bias, S, P,
                                        out, n_nodes);
}

// Round 3
// 31.003 us; speedup vs baseline: 1.6261x; 1.5590x over previous
//
#include <hip/hip_runtime.h>
#include <hip/hip_fp16.h>

#define N_REL 201   // NUM_RELS + 1 (PAD row 200 is all-zero)
#define SEM 32      // SEM_DIM
#define KNEI 20     // K neighbors
#define NROW (2 * N_REL)         // 402 P rows (dir 0 = out, dir 1 = in)

// Workspace layout:
//   [0, 80896)        __half S[201*201] (80802 B used)
//   [80896, +25728)   __half P[402][32]  (swizzled 16B segments, bias folded)
#define S_BYTES 80896
#define S_U4 5051                 // uint4 staged (80816 B >= 80802)
#define P_HALFS (NROW * SEM)      // 12864
#define P_U4 (P_HALFS * 2 / 16)   // 1608

// ---------------------------------------------------------------------------
// Kernel 1: S = rel_emb @ rel_emb^T (fp16);
//           P[dir][i][j] = rel_emb[i]·W_dir_j + 0.5*bias[j]  (fp16, swizzled).
// Swizzle: logical 16B-segment sg of row r stored at physical sg ^ ((r>>1)&3).
// ---------------------------------------------------------------------------
__global__ __launch_bounds__(256) void build_tables_kernel(
    const float* __restrict__ rel_emb,   // [201][64]
    const float* __restrict__ w,         // [32][128]
    const float* __restrict__ bias,      // [32]
    __half* __restrict__ S,              // [201][201]
    __half* __restrict__ P)              // [402][32] swizzled
{
  __shared__ float embL[N_REL * 65];
  __shared__ float wL[SEM * 129];
  const int t = threadIdx.x;
  for (int e = t; e < N_REL * 64; e += 256) {
    int r = e >> 6, d = e & 63;
    embL[r * 65 + d] = rel_emb[e];
  }
  for (int e = t; e < SEM * 128; e += 256) {
    int r = e >> 7, c = e & 127;
    wL[r * 129 + c] = w[e];
  }
  __syncthreads();

  const int i = blockIdx.x;  // 0..200
  for (int jj = t; jj < N_REL; jj += 256) {
    float acc = 0.f;
#pragma unroll
    for (int d = 0; d < 64; ++d)
      acc = fmaf(embL[i * 65 + d], embL[jj * 65 + d], acc);
    S[i * N_REL + jj] = __float2half(acc);
  }
  if (t < 64) {
    int hh = t >> 5, jj = t & 31;
    float acc = 0.5f * bias[jj];
#pragma unroll
    for (int d = 0; d < 64; ++d)
      acc = fmaf(embL[i * 65 + d], wL[jj * 129 + hh * 64 + d], acc);
    const int row = hh * N_REL + i;
    const int col = (((jj >> 3) ^ ((row >> 1) & 3)) << 3) | (jj & 7);
    P[row * SEM + col] = __float2half(acc);
  }
}

// ---------------------------------------------------------------------------
// Kernel 2: NODE-PER-LANE. Each thread owns one node; everything lane-local.
//   - 20 idx per dir via 5 uint4 loads (80B, aligned)
//   - 20 S gathers (ds_read_u16, random banks) -> registers
//   - local softmax: 19 v_max + 20 v_exp, zero cross-lane ops
//   - agg: 20 rows x 4 ds_read_b128 (swizzled fp16 P) x 16 hfma2
//   - sigmoid (32/lane) + 256B contiguous store per lane
// LDS = 80816 + 25728 = 106544 B -> 1 block/CU, 256 thr = 1 wave/SIMD.
// ---------------------------------------------------------------------------
__global__ __launch_bounds__(256) void fuse_kernel(
    const int* __restrict__ out_nei, const int* __restrict__ in_nei,
    const int* __restrict__ target, const float* __restrict__ feat,
    const __half* __restrict__ Sg, const __half* __restrict__ Pg,
    float* __restrict__ out, int n_nodes)
{
  __shared__ __align__(16) __half S_l[S_U4 * 8];   // 80816 B
  __shared__ __align__(16) __half P_l[P_HALFS];    // 25728 B
  const int t = threadIdx.x;
  {
    const uint4* s4 = (const uint4*)Sg;
    uint4* sl = (uint4*)S_l;
    for (int e = t; e < S_U4; e += 256) sl[e] = s4[e];
    const uint4* p4 = (const uint4*)Pg;
    uint4* pl = (uint4*)P_l;
    for (int e = t; e < P_U4; e += 256) pl[e] = p4[e];
  }
  __syncthreads();

  const int n = blockIdx.x * 256 + t;
  if (n >= n_nodes) return;

  const int tgt = target[n];
  // prefetch feat row early (HBM latency hides under compute)
  float4 fv[8];
  {
    const float4* frow = (const float4*)(feat + (size_t)n * SEM);
#pragma unroll
    for (int r = 0; r < 8; ++r) fv[r] = frow[r];
  }

  __half2 acc[16];
#pragma unroll
  for (int m = 0; m < 16; ++m) acc[m] = __float2half2_rn(0.f);

#pragma unroll
  for (int dir = 0; dir < 2; ++dir) {
    const int* __restrict__ nei = dir ? in_nei : out_nei;
    int idxA[KNEI];
#pragma unroll
    for (int r = 0; r < 5; ++r) {
      const uint4 v = ((const uint4*)(nei + (size_t)n * KNEI))[r];
      idxA[4 * r + 0] = (int)v.x;
      idxA[4 * r + 1] = (int)v.y;
      idxA[4 * r + 2] = (int)v.z;
      idxA[4 * r + 3] = (int)v.w;
    }
    float e[KNEI];
#pragma unroll
    for (int k = 0; k < KNEI; ++k)
      e[k] = __half2float(S_l[idxA[k] * N_REL + tgt]);
    float mx = e[0];
#pragma unroll
    for (int k = 1; k < KNEI; ++k) mx = fmaxf(mx, e[k]);
    float s = 0.f;
#pragma unroll
    for (int k = 0; k < KNEI; ++k) {
      e[k] = __expf(e[k] - mx);
      s += e[k];
    }
    const float inv = __fdividef(1.f, s);
    __half2 a2[KNEI];
#pragma unroll
    for (int k = 0; k < KNEI; ++k) a2[k] = __float2half2_rn(e[k] * inv);

#pragma unroll
    for (int k = 0; k < KNEI; ++k) {
      const int row = dir * N_REL + idxA[k];
      const int sw = (row >> 1) & 3;
      const int rb = row * SEM;
#pragma unroll
      for (int sg = 0; sg < 4; ++sg) {
        const uint4 q = *(const uint4*)&P_l[rb + ((sg ^ sw) << 3)];
        acc[4 * sg + 0] = __hfma2(a2[k], *(const __half2*)&q.x, acc[4 * sg + 0]);
        acc[4 * sg + 1] = __hfma2(a2[k], *(const __half2*)&q.y, acc[4 * sg + 1]);
        acc[4 * sg + 2] = __hfma2(a2[k], *(const __half2*)&q.z, acc[4 * sg + 2]);
        acc[4 * sg + 3] = __hfma2(a2[k], *(const __half2*)&q.w, acc[4 * sg + 3]);
      }
    }
  }

  float* orow = out + (size_t)n * 64;
#pragma unroll
  for (int r = 0; r < 8; ++r) ((float4*)orow)[r] = fv[r];
#pragma unroll
  for (int r = 0; r < 8; ++r) {
    const float v0 = __low2float(acc[2 * r]);
    const float v1 = __high2float(acc[2 * r]);
    const float v2 = __low2float(acc[2 * r + 1]);
    const float v3 = __high2float(acc[2 * r + 1]);
    float4 sgv;
    sgv.x = __fdividef(1.f, 1.f + __expf(-v0));
    sgv.y = __fdividef(1.f, 1.f + __expf(-v1));
    sgv.z = __fdividef(1.f, 1.f + __expf(-v2));
    sgv.w = __fdividef(1.f, 1.f + __expf(-v3));
    ((float4*)orow)[8 + r] = sgv;
  }
}

extern "C" void kernel_launch(void* const* d_in, const int* in_sizes, int n_in,
                              void* d_out, int out_size, void* d_ws, size_t ws_size,
                              hipStream_t stream) {
  const int* out_nei   = (const int*)d_in[0];
  const int* in_nei    = (const int*)d_in[1];
  const int* target    = (const int*)d_in[2];
  const float* feat    = (const float*)d_in[3];
  const float* rel_emb = (const float*)d_in[4];
  const float* w       = (const float*)d_in[5];
  const float* bias    = (const float*)d_in[6];
  float* out = (float*)d_out;
  const int n_nodes = in_sizes[2];

  __half* S = (__half*)d_ws;
  __half* P = (__half*)((char*)d_ws + S_BYTES);

  build_tables_kernel<<<N_REL, 256, 0, stream>>>(rel_emb, w, bias, S, P);
  const int nb = (n_nodes + 255) / 256;
  fuse_kernel<<<nb, 256, 0, stream>>>(out_nei, in_nei, target, feat, S, P,
                                      out, n_nodes);
}

// Round 4
// 23.002 us; speedup vs baseline: 2.1917x; 1.3478x over previous
//
#include <hip/hip_runtime.h>
#include <hip/hip_fp16.h>

#define N_REL 201   // NUM_RELS + 1 (PAD row 200 is all-zero)
#define N_TGT 200   // target_rels < 200
#define SEM 32      // SEM_DIM
#define KNEI 20     // K neighbors
#define PSTRIDE 40  // halfs per P row (80 B -> 8 bank-phase classes)

// Workspace layout:
//   [0, 80400)        __half S[201][200]
//   [80400, +32160)   __half P[402][PSTRIDE] (cols 0..31 valid, bias/2 folded)
#define S_BYTES 80400
#define S_U4 (S_BYTES / 16)            // 5025
#define P_HALFS (2 * N_REL * PSTRIDE)  // 16080
#define P_U4 (P_HALFS * 2 / 16)        // 2010

// ---------------------------------------------------------------------------
// Kernel 1: S[i][j] = rel_emb[i]·rel_emb[j] (fp16, j<200);
//           P[dir*201+i][c] = rel_emb[i]·W_dir_c + 0.5*bias[c] (fp16)
// ---------------------------------------------------------------------------
__global__ __launch_bounds__(256) void build_tables_kernel(
    const float* __restrict__ rel_emb,   // [201][64]
    const float* __restrict__ w,         // [32][128]
    const float* __restrict__ bias,      // [32]
    __half* __restrict__ S,              // [201][200]
    __half* __restrict__ P)              // [402][PSTRIDE]
{
  __shared__ float embL[N_REL * 65];
  __shared__ float wL[SEM * 129];
  const int t = threadIdx.x;
  for (int e = t; e < N_REL * 64; e += 256) {
    int r = e >> 6, d = e & 63;
    embL[r * 65 + d] = rel_emb[e];
  }
  for (int e = t; e < SEM * 128; e += 256) {
    int r = e >> 7, c = e & 127;
    wL[r * 129 + c] = w[e];
  }
  __syncthreads();

  const int i = blockIdx.x;  // 0..200
  for (int jj = t; jj < N_TGT; jj += 256) {
    float acc = 0.f;
#pragma unroll
    for (int d = 0; d < 64; ++d)
      acc = fmaf(embL[i * 65 + d], embL[jj * 65 + d], acc);
    S[i * N_TGT + jj] = __float2half(acc);
  }
  if (t < 64) {
    int hh = t >> 5, jj = t & 31;
    float acc = 0.5f * bias[jj];
#pragma unroll
    for (int d = 0; d < 64; ++d)
      acc = fmaf(embL[i * 65 + d], wL[jj * 129 + hh * 64 + d], acc);
    P[(hh * N_REL + i) * PSTRIDE + jj] = __float2half(acc);
  }
}

// ---------------------------------------------------------------------------
// Kernel 2: 4 LANES PER NODE. lane sub = (dir = sub>>1, h = sub&1: 16-dim half)
//   - each lane: 20 idx (5 uint4), 20 S gathers (LDS), LOCAL softmax (dup x2)
//   - agg: 20 rows x 2 ds_read_b128 (its 16 dims) -> 8 half2 acc
//   - combine dirs: 8 x shfl_xor(2); dir1 lanes sigmoid, dir0 lanes copy feat
// LDS = 80400 (S) + 32160 (P) = 112560 B -> 1 block/CU; 1024 thr = 4 waves/SIMD.
// grid = 196 blocks of 256 nodes each -> balanced 1 block/CU.
// ---------------------------------------------------------------------------
__global__ __launch_bounds__(1024, 4) void fuse_kernel(
    const int* __restrict__ out_nei, const int* __restrict__ in_nei,
    const int* __restrict__ target, const float* __restrict__ feat,
    const __half* __restrict__ Sg, const __half* __restrict__ Pg,
    float* __restrict__ out, int n_nodes)
{
  __shared__ __align__(16) __half S_l[S_U4 * 8];   // 80400 B
  __shared__ __align__(16) __half P_l[P_HALFS];    // 32160 B
  const int t = threadIdx.x;
  {
    const uint4* s4 = (const uint4*)Sg;
    uint4* sl = (uint4*)S_l;
    for (int e = t; e < S_U4; e += 1024) sl[e] = s4[e];
    const uint4* p4 = (const uint4*)Pg;
    uint4* pl = (uint4*)P_l;
    for (int e = t; e < P_U4; e += 1024) pl[e] = p4[e];
  }
  __syncthreads();

  const int gid = blockIdx.x * 1024 + t;
  const int n = gid >> 2;
  if (n >= n_nodes) return;
  const int sub = t & 3;
  const int dir = sub >> 1;   // 0 = out, 1 = in
  const int h = sub & 1;      // which 16 output dims

  const int tgt = target[n];  // quad-uniform -> broadcast
  const int* __restrict__ nei = dir ? in_nei : out_nei;

  int idxA[KNEI];
#pragma unroll
  for (int r = 0; r < 5; ++r) {
    const uint4 v = ((const uint4*)(nei + (size_t)n * KNEI))[r];
    idxA[4 * r + 0] = (int)v.x;
    idxA[4 * r + 1] = (int)v.y;
    idxA[4 * r + 2] = (int)v.z;
    idxA[4 * r + 3] = (int)v.w;
  }
  float ev[KNEI];
#pragma unroll
  for (int k = 0; k < KNEI; ++k)
    ev[k] = __half2float(S_l[idxA[k] * N_TGT + tgt]);
  float mx = ev[0];
#pragma unroll
  for (int k = 1; k < KNEI; ++k) mx = fmaxf(mx, ev[k]);
  float s = 0.f;
#pragma unroll
  for (int k = 0; k < KNEI; ++k) {
    ev[k] = __expf(ev[k] - mx);
    s += ev[k];
  }
  const float inv = __fdividef(1.f, s);

  __half2 acc[8];
#pragma unroll
  for (int m = 0; m < 8; ++m) acc[m] = __float2half2_rn(0.f);
#pragma unroll
  for (int k = 0; k < KNEI; ++k) {
    const __half2 a2 = __float2half2_rn(ev[k] * inv);
    const int rb = (dir * N_REL + idxA[k]) * PSTRIDE + h * 16;
    const uint4 q0 = *(const uint4*)&P_l[rb];
    const uint4 q1 = *(const uint4*)&P_l[rb + 8];
    acc[0] = __hfma2(a2, *(const __half2*)&q0.x, acc[0]);
    acc[1] = __hfma2(a2, *(const __half2*)&q0.y, acc[1]);
    acc[2] = __hfma2(a2, *(const __half2*)&q0.z, acc[2]);
    acc[3] = __hfma2(a2, *(const __half2*)&q0.w, acc[3]);
    acc[4] = __hfma2(a2, *(const __half2*)&q1.x, acc[4]);
    acc[5] = __hfma2(a2, *(const __half2*)&q1.y, acc[5]);
    acc[6] = __hfma2(a2, *(const __half2*)&q1.z, acc[6]);
    acc[7] = __hfma2(a2, *(const __half2*)&q1.w, acc[7]);
  }
  // combine the two directions: partner lane = lane^2 (same node, same h)
  float tv[16];
#pragma unroll
  for (int m = 0; m < 8; ++m) {
    const unsigned int u = *(const unsigned int*)&acc[m];
    const unsigned int v = __shfl_xor(u, 2, 64);
    const __half2 tot = __hadd2(acc[m], *(const __half2*)&v);
    tv[2 * m]     = __low2float(tot);
    tv[2 * m + 1] = __high2float(tot);
  }

  float* orow = out + (size_t)n * 64;
  if (dir) {
    // write 16 sigmoid outputs at [32 + h*16, +16)
    float4 sg[4];
#pragma unroll
    for (int r = 0; r < 4; ++r) {
      sg[r].x = __fdividef(1.f, 1.f + __expf(-tv[4 * r + 0]));
      sg[r].y = __fdividef(1.f, 1.f + __expf(-tv[4 * r + 1]));
      sg[r].z = __fdividef(1.f, 1.f + __expf(-tv[4 * r + 2]));
      sg[r].w = __fdividef(1.f, 1.f + __expf(-tv[4 * r + 3]));
    }
#pragma unroll
    for (int r = 0; r < 4; ++r)
      ((float4*)(orow + SEM + h * 16))[r] = sg[r];
  } else {
    // copy 16 feat values to [h*16, +16)
    const float4* frow = (const float4*)(feat + (size_t)n * SEM + h * 16);
#pragma unroll
    for (int r = 0; r < 4; ++r)
      ((float4*)(orow + h * 16))[r] = frow[r];
  }
}

extern "C" void kernel_launch(void* const* d_in, const int* in_sizes, int n_in,
                              void* d_out, int out_size, void* d_ws, size_t ws_size,
                              hipStream_t stream) {
  const int* out_nei   = (const int*)d_in[0];
  const int* in_nei    = (const int*)d_in[1];
  const int* target    = (const int*)d_in[2];
  const float* feat    = (const float*)d_in[3];
  const float* rel_emb = (const float*)d_in[4];
  const float* w       = (const float*)d_in[5];
  const float* bias    = (const float*)d_in[6];
  float* out = (float*)d_out;
  const int n_nodes = in_sizes[2];

  __half* S = (__half*)d_ws;
  __half* P = (__half*)((char*)d_ws + S_BYTES);

  build_tables_kernel<<<N_REL, 256, 0, stream>>>(rel_emb, w, bias, S, P);
  const int threads_total = n_nodes * 4;
  const int nb = (threads_total + 1023) / 1024;
  fuse_kernel<<<nb, 1024, 0, stream>>>(out_nei, in_nei, target, feat, S, P,
                                       out, n_nodes);
}

// Round 5
// 22.563 us; speedup vs baseline: 2.2344x; 1.0195x over previous
//
#include <hip/hip_runtime.h>
#include <hip/hip_fp16.h>

#define N_REL 201   // NUM_RELS + 1 (PAD row 200 is all-zero)
#define N_TGT 200   // target_rels < 200
#define SEM 32      // SEM_DIM
#define KNEI 20     // K neighbors
#define PSTRIDE 40  // halfs per P row (80 B -> 8 bank-phase classes)

// Workspace layout:
//   [0, 80400)        __half S_T[200][201]   (S_T[tgt][idx] = emb_idx . emb_tgt)
//   [80400, +32160)   __half P[402][PSTRIDE] (cols 0..31 valid, bias/2 folded)
#define ST_BYTES 80400               // = 16 * 5025, so P offset is 16B-aligned
#define P_HALFS (2 * N_REL * PSTRIDE)  // 16080
#define P_U4 (P_HALFS * 2 / 16)        // 2010

// ---------------------------------------------------------------------------
// Kernel 1: S_T[j][i] = rel_emb[i]·rel_emb[j] (fp16, j<200, i<201);
//           P[dir*201+i][c] = rel_emb[i]·W_dir_c + 0.5*bias[c] (fp16)
// ---------------------------------------------------------------------------
__global__ __launch_bounds__(256) void build_tables_kernel(
    const float* __restrict__ rel_emb,   // [201][64]
    const float* __restrict__ w,         // [32][128]
    const float* __restrict__ bias,      // [32]
    __half* __restrict__ St,             // [200][201] transposed
    __half* __restrict__ P)              // [402][PSTRIDE]
{
  __shared__ float embL[N_REL * 65];
  __shared__ float wL[SEM * 129];
  const int t = threadIdx.x;
  for (int e = t; e < N_REL * 64; e += 256) {
    int r = e >> 6, d = e & 63;
    embL[r * 65 + d] = rel_emb[e];
  }
  for (int e = t; e < SEM * 128; e += 256) {
    int r = e >> 7, c = e & 127;
    wL[r * 129 + c] = w[e];
  }
  __syncthreads();

  const int i = blockIdx.x;  // 0..200 (idx dimension)
  for (int jj = t; jj < N_TGT; jj += 256) {
    float acc = 0.f;
#pragma unroll
    for (int d = 0; d < 64; ++d)
      acc = fmaf(embL[i * 65 + d], embL[jj * 65 + d], acc);
    St[jj * N_REL + i] = __float2half(acc);   // transposed store
  }
  if (t < 64) {
    int hh = t >> 5, jj = t & 31;
    float acc = 0.5f * bias[jj];
#pragma unroll
    for (int d = 0; d < 64; ++d)
      acc = fmaf(embL[i * 65 + d], wL[jj * 129 + hh * 64 + d], acc);
    P[(hh * N_REL + i) * PSTRIDE + jj] = __float2half(acc);
  }
}

// ---------------------------------------------------------------------------
// Kernel 2: 8 LANES PER NODE. sub = t&7: dir = sub>>2, q = sub&3 (8-dim slice).
//   - lane loads 5 idx; gathers 5 scores from GLOBAL S_T (one 402B row/node:
//     L1/L2 line reuse), quad softmax via shfl_xor(1,2) (DPP-cheap)
//   - packs {idx,w_fp16} x5, quad all-gather (15 shuffles) -> 20 pairs/lane
//   - agg: 20 x ds_read_b128 (own 8-dim slice of P row) + 4 hfma2 each
//   - cross-dir: 4 x shfl_xor(4); lanes 0-3 write feat, 4-7 write sigmoid
// LDS = P only (32160 B) -> ~5 blocks/CU resident, 20 waves/CU, 1563 blocks
// dynamically balanced over all 256 CUs.
// ---------------------------------------------------------------------------
__global__ __launch_bounds__(256, 5) void fuse_kernel(
    const int* __restrict__ out_nei, const int* __restrict__ in_nei,
    const int* __restrict__ target, const float* __restrict__ feat,
    const __half* __restrict__ St, const __half* __restrict__ Pg,
    float* __restrict__ out, int n_nodes)
{
  __shared__ __align__(16) __half P_l[P_HALFS];    // 32160 B
  const int t = threadIdx.x;
  const int gid = blockIdx.x * 256 + t;
  const int n = gid >> 3;
  const int sub = t & 7;
  const int dir = sub >> 2;   // 0 = out, 1 = in
  const int q = sub & 3;      // 8-dim slice
  const bool active = (n < n_nodes);

  // ---- issue node-data loads early (hide HBM latency under staging) ----
  int tgt = 0;
  int idxA[5];
  float4 f0, f1;
  if (active) {
    tgt = target[n];
    const int* __restrict__ nei = dir ? in_nei : out_nei;
#pragma unroll
    for (int i = 0; i < 5; ++i) idxA[i] = nei[(size_t)n * KNEI + q * 5 + i];
    if (dir == 0) {
      const float4* frow = (const float4*)(feat + (size_t)n * SEM + q * 8);
      f0 = frow[0];
      f1 = frow[1];
    }
  }

  // ---- stage P into LDS ----
  {
    const uint4* p4 = (const uint4*)Pg;
    uint4* pl = (uint4*)P_l;
    for (int e = t; e < P_U4; e += 256) pl[e] = p4[e];
  }
  __syncthreads();
  if (!active) return;

  // ---- gather 5 scores from global S_T (row tgt, hot in L1/L2) ----
  float ev[5];
  const __half* __restrict__ srow = St + (size_t)tgt * N_REL;
#pragma unroll
  for (int i = 0; i < 5; ++i) ev[i] = __half2float(srow[idxA[i]]);

  // ---- softmax over the dir's 20 scores (quad butterfly) ----
  float mx = ev[0];
#pragma unroll
  for (int i = 1; i < 5; ++i) mx = fmaxf(mx, ev[i]);
  mx = fmaxf(mx, __shfl_xor(mx, 1, 64));
  mx = fmaxf(mx, __shfl_xor(mx, 2, 64));
  float s = 0.f;
#pragma unroll
  for (int i = 0; i < 5; ++i) {
    ev[i] = __expf(ev[i] - mx);
    s += ev[i];
  }
  s += __shfl_xor(s, 1, 64);
  s += __shfl_xor(s, 2, 64);
  const float inv = __fdividef(1.f, s);

  // ---- pack {idx | w_fp16} and all-gather within the dir quad ----
  unsigned int pk[20];
#pragma unroll
  for (int i = 0; i < 5; ++i) {
    const __half hw = __float2half(ev[i] * inv);
    pk[i] = ((unsigned int)idxA[i] << 16) | (unsigned int)__half_as_ushort(hw);
  }
#pragma unroll
  for (int i = 0; i < 5; ++i) pk[5 + i] = __shfl_xor(pk[i], 1, 64);
#pragma unroll
  for (int i = 0; i < 10; ++i) pk[10 + i] = __shfl_xor(pk[i], 2, 64);

  // ---- aggregate 20 rows, own 8-dim slice (1 b128 per row) ----
  __half2 acc[4];
#pragma unroll
  for (int m = 0; m < 4; ++m) acc[m] = __float2half2_rn(0.f);
  const int dbase = dir * (N_REL * PSTRIDE) + q * 8;
#pragma unroll
  for (int i = 0; i < 20; ++i) {
    const int idx = (int)(pk[i] >> 16);
    const unsigned int lo = pk[i] & 0xFFFFu;
    const unsigned int dd = lo | (lo << 16);
    const __half2 a2 = *(const __half2*)&dd;
    const uint4 qv = *(const uint4*)&P_l[dbase + idx * PSTRIDE];
    acc[0] = __hfma2(a2, *(const __half2*)&qv.x, acc[0]);
    acc[1] = __hfma2(a2, *(const __half2*)&qv.y, acc[1]);
    acc[2] = __hfma2(a2, *(const __half2*)&qv.z, acc[2]);
    acc[3] = __hfma2(a2, *(const __half2*)&qv.w, acc[3]);
  }

  // ---- combine directions: partner lane = lane ^ 4 ----
#pragma unroll
  for (int m = 0; m < 4; ++m) {
    const unsigned int u = *(const unsigned int*)&acc[m];
    const unsigned int v = __shfl_xor(u, 4, 64);
    acc[m] = __hadd2(acc[m], *(const __half2*)&v);
  }

  // ---- write: lanes 0-3 -> feat[q*8..], lanes 4-7 -> sigmoid sem[q*8..] ----
  float* orow = out + (size_t)n * 64 + sub * 8;
  if (dir == 0) {
    ((float4*)orow)[0] = f0;
    ((float4*)orow)[1] = f1;
  } else {
    float tv[8];
#pragma unroll
    for (int m = 0; m < 4; ++m) {
      tv[2 * m]     = __low2float(acc[m]);
      tv[2 * m + 1] = __high2float(acc[m]);
    }
    float4 s0, s1;
    s0.x = __fdividef(1.f, 1.f + __expf(-tv[0]));
    s0.y = __fdividef(1.f, 1.f + __expf(-tv[1]));
    s0.z = __fdividef(1.f, 1.f + __expf(-tv[2]));
    s0.w = __fdividef(1.f, 1.f + __expf(-tv[3]));
    s1.x = __fdividef(1.f, 1.f + __expf(-tv[4]));
    s1.y = __fdividef(1.f, 1.f + __expf(-tv[5]));
    s1.z = __fdividef(1.f, 1.f + __expf(-tv[6]));
    s1.w = __fdividef(1.f, 1.f + __expf(-tv[7]));
    ((float4*)orow)[0] = s0;
    ((float4*)orow)[1] = s1;
  }
}

extern "C" void kernel_launch(void* const* d_in, const int* in_sizes, int n_in,
                              void* d_out, int out_size, void* d_ws, size_t ws_size,
                              hipStream_t stream) {
  const int* out_nei   = (const int*)d_in[0];
  const int* in_nei    = (const int*)d_in[1];
  const int* target    = (const int*)d_in[2];
  const float* feat    = (const float*)d_in[3];
  const float* rel_emb = (const float*)d_in[4];
  const float* w       = (const float*)d_in[5];
  const float* bias    = (const float*)d_in[6];
  float* out = (float*)d_out;
  const int n_nodes = in_sizes[2];

  __half* St = (__half*)d_ws;
  __half* P  = (__half*)((char*)d_ws + ST_BYTES);

  build_tables_kernel<<<N_REL, 256, 0, stream>>>(rel_emb, w, bias, St, P);
  const int total_threads = n_nodes * 8;
  const int nb = (total_threads + 255) / 256;   // 1563 blocks @ N=50000
  fuse_kernel<<<nb, 256, 0, stream>>>(out_nei, in_nei, target, feat, St, P,
                                      out, n_nodes);
}

// Round 7
// 20.790 us; speedup vs baseline: 2.4249x; 1.0853x over previous
//
#include <hip/hip_runtime.h>
#include <hip/hip_fp16.h>

#define N_REL 201   // NUM_RELS + 1 (PAD row 200 is all-zero)
#define N_TGT 200   // target_rels < 200
#define SEM 32      // SEM_DIM
#define KNEI 20     // K neighbors
#define PSTRIDE 40  // halfs per P row (80 B -> uniform 8-class bank phases)

typedef float floatx4 __attribute__((ext_vector_type(4)));  // NT-builtin-compatible

// Workspace layout:
//   [0, 80400)        __half S_T[200][201]   (S_T[tgt][idx] = emb_idx . emb_tgt)
//   [80400, +32160)   __half P[402][PSTRIDE] (cols 0..31 valid, bias/2 folded)
#define ST_BYTES 80400                 // 16-aligned (16*5025)
#define P_HALFS (2 * N_REL * PSTRIDE)  // 16080
#define P_U4 (P_HALFS * 2 / 16)        // 2010

// ---------------------------------------------------------------------------
// Kernel 1: S_T[j][i] = rel_emb[i]·rel_emb[j] (fp16); P rows with bias/2 folded.
// ---------------------------------------------------------------------------
__global__ __launch_bounds__(256) void build_tables_kernel(
    const float* __restrict__ rel_emb,   // [201][64]
    const float* __restrict__ w,         // [32][128]
    const float* __restrict__ bias,      // [32]
    __half* __restrict__ St,             // [200][201] transposed
    __half* __restrict__ P)              // [402][PSTRIDE]
{
  __shared__ float embL[N_REL * 65];
  __shared__ float wL[SEM * 129];
  const int t = threadIdx.x;
  for (int e = t; e < N_REL * 64; e += 256) {
    int r = e >> 6, d = e & 63;
    embL[r * 65 + d] = rel_emb[e];
  }
  for (int e = t; e < SEM * 128; e += 256) {
    int r = e >> 7, c = e & 127;
    wL[r * 129 + c] = w[e];
  }
  __syncthreads();

  const int i = blockIdx.x;  // 0..200 (idx dimension)
  for (int jj = t; jj < N_TGT; jj += 256) {
    float acc = 0.f;
#pragma unroll
    for (int d = 0; d < 64; ++d)
      acc = fmaf(embL[i * 65 + d], embL[jj * 65 + d], acc);
    St[jj * N_REL + i] = __float2half(acc);   // transposed store
  }
  if (t < 64) {
    int hh = t >> 5, jj = t & 31;
    float acc = 0.5f * bias[jj];
#pragma unroll
    for (int d = 0; d < 64; ++d)
      acc = fmaf(embL[i * 65 + d], wL[jj * 129 + hh * 64 + d], acc);
    P[(hh * N_REL + i) * PSTRIDE + jj] = __float2half(acc);
  }
}

// ---------------------------------------------------------------------------
// Kernel 2: 8 LANES PER NODE, 512-thr blocks (64 nodes/block, 782 blocks).
// Latency schedule: issue tgt/idx/S-gather/feat loads FIRST, then stage P
// (staging + barrier hides the gather chain), then pure register compute.
// ---------------------------------------------------------------------------
__global__ __launch_bounds__(512, 4) void fuse_kernel(
    const int* __restrict__ out_nei, const int* __restrict__ in_nei,
    const int* __restrict__ target, const float* __restrict__ feat,
    const __half* __restrict__ St, const __half* __restrict__ Pg,
    float* __restrict__ out, int n_nodes)
{
  __shared__ __align__(16) __half P_l[P_HALFS];    // 32160 B
  const int t = threadIdx.x;
  const int gid = blockIdx.x * 512 + t;
  const int n = gid >> 3;
  const int sub = t & 7;
  const int dir = sub >> 2;   // 0 = out, 1 = in
  const int q = sub & 3;      // 8-dim slice
  const bool active = (n < n_nodes);

  // ---- phase 1: issue ALL dependent-chain loads (latency hides under staging)
  int idxA[5];
  unsigned short sv[5];
  floatx4 f0, f1;
  if (active) {
    const int tgt = target[n];
    const int* __restrict__ nei = dir ? in_nei : out_nei;
#pragma unroll
    for (int i = 0; i < 5; ++i) idxA[i] = nei[(size_t)n * KNEI + q * 5 + i];
    const __half* __restrict__ srow = St + (size_t)tgt * N_REL;
#pragma unroll
    for (int i = 0; i < 5; ++i)
      sv[i] = *(const unsigned short*)&srow[idxA[i]];
    if (dir == 0) {
      const floatx4* frow = (const floatx4*)(feat + (size_t)n * SEM + q * 8);
      f0 = __builtin_nontemporal_load(frow);
      f1 = __builtin_nontemporal_load(frow + 1);
    }
  }

  // ---- phase 2: stage P into LDS (covers phase-1 latency) ----
  {
    const uint4* p4 = (const uint4*)Pg;
    uint4* pl = (uint4*)P_l;
    for (int e = t; e < P_U4; e += 512) pl[e] = p4[e];
  }
  __syncthreads();
  if (!active) return;

  // ---- phase 3: register-resident compute ----
  float ev[5];
#pragma unroll
  for (int i = 0; i < 5; ++i) ev[i] = __half2float(__ushort_as_half(sv[i]));

  // softmax over the dir's 20 scores (quad butterfly, DPP-cheap)
  float mx = ev[0];
#pragma unroll
  for (int i = 1; i < 5; ++i) mx = fmaxf(mx, ev[i]);
  mx = fmaxf(mx, __shfl_xor(mx, 1, 64));
  mx = fmaxf(mx, __shfl_xor(mx, 2, 64));
  float s = 0.f;
#pragma unroll
  for (int i = 0; i < 5; ++i) {
    ev[i] = __expf(ev[i] - mx);
    s += ev[i];
  }
  s += __shfl_xor(s, 1, 64);
  s += __shfl_xor(s, 2, 64);
  const float inv = __fdividef(1.f, s);

  // pack {idx | w_fp16}; all-gather within the dir quad (15 shuffles)
  unsigned int pk[20];
#pragma unroll
  for (int i = 0; i < 5; ++i) {
    const __half hw = __float2half(ev[i] * inv);
    pk[i] = ((unsigned int)idxA[i] << 16) | (unsigned int)__half_as_ushort(hw);
  }
#pragma unroll
  for (int i = 0; i < 5; ++i) pk[5 + i] = __shfl_xor(pk[i], 1, 64);
#pragma unroll
  for (int i = 0; i < 10; ++i) pk[10 + i] = __shfl_xor(pk[i], 2, 64);

  // aggregate 20 rows, own 8-dim slice (1 b128 per row)
  __half2 acc[4];
#pragma unroll
  for (int m = 0; m < 4; ++m) acc[m] = __float2half2_rn(0.f);
  const int dbase = dir * (N_REL * PSTRIDE) + q * 8;
#pragma unroll
  for (int i = 0; i < 20; ++i) {
    const int idx = (int)(pk[i] >> 16);
    const unsigned int lo = pk[i] & 0xFFFFu;
    const unsigned int dd = lo | (lo << 16);
    const __half2 a2 = *(const __half2*)&dd;
    const uint4 qv = *(const uint4*)&P_l[dbase + idx * PSTRIDE];
    acc[0] = __hfma2(a2, *(const __half2*)&qv.x, acc[0]);
    acc[1] = __hfma2(a2, *(const __half2*)&qv.y, acc[1]);
    acc[2] = __hfma2(a2, *(const __half2*)&qv.z, acc[2]);
    acc[3] = __hfma2(a2, *(const __half2*)&qv.w, acc[3]);
  }

  // combine directions: partner lane = lane ^ 4
#pragma unroll
  for (int m = 0; m < 4; ++m) {
    const unsigned int u = *(const unsigned int*)&acc[m];
    const unsigned int v = __shfl_xor(u, 4, 64);
    acc[m] = __hadd2(acc[m], *(const __half2*)&v);
  }

  // write: lanes 0-3 -> feat slice, lanes 4-7 -> sigmoid sem slice (NT stores)
  float* orow = out + (size_t)n * 64 + sub * 8;
  if (dir == 0) {
    __builtin_nontemporal_store(f0, (floatx4*)orow);
    __builtin_nontemporal_store(f1, (floatx4*)orow + 1);
  } else {
    float tv[8];
#pragma unroll
    for (int m = 0; m < 4; ++m) {
      tv[2 * m]     = __low2float(acc[m]);
      tv[2 * m + 1] = __high2float(acc[m]);
    }
    floatx4 s0, s1;
    s0.x = __fdividef(1.f, 1.f + __expf(-tv[0]));
    s0.y = __fdividef(1.f, 1.f + __expf(-tv[1]));
    s0.z = __fdividef(1.f, 1.f + __expf(-tv[2]));
    s0.w = __fdividef(1.f, 1.f + __expf(-tv[3]));
    s1.x = __fdividef(1.f, 1.f + __expf(-tv[4]));
    s1.y = __fdividef(1.f, 1.f + __expf(-tv[5]));
    s1.z = __fdividef(1.f, 1.f + __expf(-tv[6]));
    s1.w = __fdividef(1.f, 1.f + __expf(-tv[7]));
    __builtin_nontemporal_store(s0, (floatx4*)orow);
    __builtin_nontemporal_store(s1, (floatx4*)orow + 1);
  }
}

extern "C" void kernel_launch(void* const* d_in, const int* in_sizes, int n_in,
                              void* d_out, int out_size, void* d_ws, size_t ws_size,
                              hipStream_t stream) {
  const int* out_nei   = (const int*)d_in[0];
  const int* in_nei    = (const int*)d_in[1];
  const int* target    = (const int*)d_in[2];
  const float* feat    = (const float*)d_in[3];
  const float* rel_emb = (const float*)d_in[4];
  const float* w       = (const float*)d_in[5];
  const float* bias    = (const float*)d_in[6];
  float* out = (float*)d_out;
  const int n_nodes = in_sizes[2];

  __half* St = (__half*)d_ws;
  __half* P  = (__half*)((char*)d_ws + ST_BYTES);

  build_tables_kernel<<<N_REL, 256, 0, stream>>>(rel_emb, w, bias, St, P);
  const int total_threads = n_nodes * 8;
  const int nb = (total_threads + 511) / 512;   // 782 blocks @ N=50000
  fuse_kernel<<<nb, 512, 0, stream>>>(out_nei, in_nei, target, feat, St, P,
                                      out, n_nodes);
}